// Round 5
// baseline (304.350 us; speedup 1.0000x reference)
//
#include <hip/hip_runtime.h>

// Problem constants: S=4096, H=3, E=512, G=3334, F=1
constexpr int S = 4096;
constexpr int H = 3;
constexpr int E = 512;
constexpr int G = 3334;
constexpr float RES = 0.03f;             // INTEGRAL_RESOLUTION
constexpr float LOG2E = 1.44269504088896340736f;

constexpr int BT   = 256;                // threads per block
constexpr int NBLK = S * H / 2;          // 6144: one block per PAIR of (s,h) rows
constexpr int GF4  = 2 * G / 4;          // 1667 float4 per row-pair (exact)
constexpr int GFULL = GF4 / BT;          // 6 full sweeps
constexpr int GTAIL = GF4 - GFULL * BT;  // 131 threads do a 7th
// events: 2 rows * 512 = 1024 floats = 256 float4 per block = 1 per thread

typedef float f4_t __attribute__((ext_vector_type(4)));
typedef int   i4_t __attribute__((ext_vector_type(4)));

template <typename T>
__device__ __forceinline__ T ntload(const T* p) {
#if __has_builtin(__builtin_nontemporal_load)
    return __builtin_nontemporal_load(p);
#else
    return *p;
#endif
}

__global__ __launch_bounds__(256) void logic_model_kernel(
    const float* __restrict__ ev,     // [S*H*E] event_features
    const int*   __restrict__ mask,   // [S*H*E] event_mask (0/1)
    const float* __restrict__ gr,     // [S*H*G] grid_features
    const float* __restrict__ w,      // [H] weights
    const float* __restrict__ bases,  // [H]
    const float* __restrict__ eff,    // [H] effects
    float* __restrict__ out)
{
    const float b0 = bases[0], b1 = bases[1], b2 = bases[2];
    const float w0 = w[0] * eff[0], w1 = w[1] * eff[1], w2 = w[2] * eff[2];
    // exp2-form constants for the integral part
    const float c0 = b0 * LOG2E, c1 = b1 * LOG2E, c2 = b2 * LOG2E;
    const float v0 = w0 * LOG2E, v1 = w1 * LOG2E, v2 = w2 * LOG2E;

    const int t = threadIdx.x;
    const int b = blockIdx.x;

    // Heads of the two rows this block owns: row0 = 2b, row1 = 2b+1 (mod 3).
    const int r2b = (2 * b) % 3;              // uniform, scalar magic-mul once
    const int h0 = r2b;
    const int h1 = (r2b == 2) ? 0 : r2b + 1;
    const float cr0 = (h0 == 0) ? c0 : ((h0 == 1) ? c1 : c2);
    const float vr0 = (h0 == 0) ? v0 : ((h0 == 1) ? v1 : v2);
    const float cr1 = (h1 == 0) ? c0 : ((h1 == 1) ? c1 : c2);
    const float vr1 = (h1 == 0) ? v0 : ((h1 == 1) ? v1 : v2);

    const f4_t* gr4 = (const f4_t*)gr;
    const f4_t* ev4 = (const f4_t*)ev;
    const i4_t* m4  = (const i4_t*)mask;

    // ---- Part 1: events. Exactly one float4 + int4 per thread. -----------
    // Block b's event f4 range [256b, 256b+256) covers rows 2b (t<128), 2b+1.
    float acc_ev = 0.f;
    {
        f4_t x = ntload(ev4 + (size_t)b * BT + t);
        i4_t m = ntload(m4  + (size_t)b * BT + t);
        const int he = (t < 128) ? h0 : h1;
        const float bb = (he == 0) ? b0 : ((he == 1) ? b1 : b2);
        const float ww = (he == 0) ? w0 : ((he == 1) ? w1 : w2);
        if (m.x) acc_ev += bb + ww * x.x;
        if (m.y) acc_ev += bb + ww * x.y;
        if (m.z) acc_ev += bb + ww * x.z;
        if (m.w) acc_ev += bb + ww * x.w;
    }

    // ---- Part 2: grid. 1667 float4 per block, contiguous stream. ---------
    // Local element j = 4*l + e; j < G -> row0 coeffs else row1. One compare
    // per element, zero integer divides.
    const int gbase = b * GF4;
    float acc_gr = 0.f;
    #pragma unroll
    for (int k = 0; k < GFULL; ++k) {
        const int l = t + k * BT;
        f4_t y = ntload(gr4 + gbase + l);
        const int j = 4 * l;
        float cA, vA;
        cA = (j     < G) ? cr0 : cr1;  vA = (j     < G) ? vr0 : vr1;
        acc_gr += exp2f(cA + vA * y.x);
        cA = (j + 1 < G) ? cr0 : cr1;  vA = (j + 1 < G) ? vr0 : vr1;
        acc_gr += exp2f(cA + vA * y.y);
        cA = (j + 2 < G) ? cr0 : cr1;  vA = (j + 2 < G) ? vr0 : vr1;
        acc_gr += exp2f(cA + vA * y.z);
        cA = (j + 3 < G) ? cr0 : cr1;  vA = (j + 3 < G) ? vr0 : vr1;
        acc_gr += exp2f(cA + vA * y.w);
    }
    if (t < GTAIL) {                          // l in [1536, 1667): all row1
        const int l = t + GFULL * BT;
        f4_t y = ntload(gr4 + gbase + l);
        acc_gr += exp2f(cr1 + vr1 * y.x);
        acc_gr += exp2f(cr1 + vr1 * y.y);
        acc_gr += exp2f(cr1 + vr1 * y.z);
        acc_gr += exp2f(cr1 + vr1 * y.w);
    }

    float v = acc_ev - RES * acc_gr;

    // ---- Block reduction: wave64 shuffle -> LDS -> one atomic per block ---
    #pragma unroll
    for (int off = 32; off > 0; off >>= 1)
        v += __shfl_down(v, off, 64);

    __shared__ float sdata[4];
    const int wave = threadIdx.x >> 6;
    const int lane = threadIdx.x & 63;
    if (lane == 0) sdata[wave] = v;
    __syncthreads();
    if (threadIdx.x == 0) {
        float s = sdata[0] + sdata[1] + sdata[2] + sdata[3];
        atomicAdd(out, s);
    }
}

extern "C" void kernel_launch(void* const* d_in, const int* in_sizes, int n_in,
                              void* d_out, int out_size, void* d_ws, size_t ws_size,
                              hipStream_t stream) {
    const float* ev    = (const float*)d_in[0];  // event_features [S,H,E,1]
    const int*   mask  = (const int*)  d_in[1];  // event_mask     [S,H,E]
    const float* gr    = (const float*)d_in[2];  // grid_features  [S,H,G,1]
    const float* wgt   = (const float*)d_in[3];  // weights        [H,1]
    const float* bases = (const float*)d_in[4];  // bases          [H]
    const float* eff   = (const float*)d_in[5];  // effects        [H,1]
    float* out = (float*)d_out;

    // d_out is poisoned 0xAA before every timed launch — zero it (capture-legal).
    hipMemsetAsync(out, 0, sizeof(float), stream);

    logic_model_kernel<<<NBLK, BT, 0, stream>>>(ev, mask, gr, wgt, bases, eff, out);
}

// Round 6
// 291.892 us; speedup vs baseline: 1.0427x; 1.0427x over previous
//
#include <hip/hip_runtime.h>

// Problem constants: S=4096, H=3, E=512, G=3334, F=1
constexpr int S = 4096;
constexpr int H = 3;
constexpr int E = 512;
constexpr int G = 3334;
constexpr float RES = 0.03f;             // INTEGRAL_RESOLUTION
constexpr float LOG2E = 1.44269504088896340736f;

constexpr int BT   = 256;                // threads per block
constexpr int NBLK = S * H / 2;          // 6144: one block per PAIR of (s,h) rows
constexpr int GF4  = 2 * G / 4;          // 1667 float4 per row-pair (exact)
constexpr int GFULL = GF4 / BT;          // 6 full sweeps
constexpr int GTAIL = GF4 - GFULL * BT;  // 131 threads do a 7th
// events: 2 rows * 512 = 1024 floats = 256 float4 per block = 1 per thread

typedef float f4_t __attribute__((ext_vector_type(4)));
typedef int   i4_t __attribute__((ext_vector_type(4)));

__global__ __launch_bounds__(256) void logic_model_kernel(
    const float* __restrict__ ev,     // [S*H*E] event_features
    const int*   __restrict__ mask,   // [S*H*E] event_mask (0/1)
    const float* __restrict__ gr,     // [S*H*G] grid_features
    const float* __restrict__ w,      // [H] weights
    const float* __restrict__ bases,  // [H]
    const float* __restrict__ eff,    // [H] effects
    float* __restrict__ out)
{
    const float b0 = bases[0], b1 = bases[1], b2 = bases[2];
    const float w0 = w[0] * eff[0], w1 = w[1] * eff[1], w2 = w[2] * eff[2];
    // exp2-form constants for the integral part
    const float c0 = b0 * LOG2E, c1 = b1 * LOG2E, c2 = b2 * LOG2E;
    const float v0 = w0 * LOG2E, v1 = w1 * LOG2E, v2 = w2 * LOG2E;

    const int t = threadIdx.x;
    const int b = blockIdx.x;

    // Heads of the two rows this block owns: row0 = 2b, row1 = 2b+1 (mod 3).
    const int r2b = (2 * b) % 3;              // uniform scalar, one magic-mul
    const int h0 = r2b;
    const int h1 = (r2b == 2) ? 0 : r2b + 1;
    const float cr0 = (h0 == 0) ? c0 : ((h0 == 1) ? c1 : c2);
    const float vr0 = (h0 == 0) ? v0 : ((h0 == 1) ? v1 : v2);
    const float cr1 = (h1 == 0) ? c0 : ((h1 == 1) ? c1 : c2);
    const float vr1 = (h1 == 0) ? v0 : ((h1 == 1) ? v1 : v2);

    const f4_t* gr4 = (const f4_t*)gr;
    const f4_t* ev4 = (const f4_t*)ev;
    const i4_t* m4  = (const i4_t*)mask;

    // ---- Part 1: events. Exactly one float4 + int4 per thread. -----------
    // Block b's event f4 range [256b, 256b+256) covers rows 2b (t<128), 2b+1.
    float acc_ev = 0.f;
    {
        f4_t x = ev4[(size_t)b * BT + t];
        i4_t m = m4[(size_t)b * BT + t];
        const int he = (t < 128) ? h0 : h1;
        const float bb = (he == 0) ? b0 : ((he == 1) ? b1 : b2);
        const float ww = (he == 0) ? w0 : ((he == 1) ? w1 : w2);
        if (m.x) acc_ev += bb + ww * x.x;
        if (m.y) acc_ev += bb + ww * x.y;
        if (m.z) acc_ev += bb + ww * x.z;
        if (m.w) acc_ev += bb + ww * x.w;
    }

    // ---- Part 2: grid. 1667 float4 per block, contiguous stream. ---------
    // Local element j = 4*l + e; j < G -> row0 coeffs else row1. One compare
    // per element, zero per-element integer divides.
    const int gbase = b * GF4;
    float acc_gr = 0.f;
    #pragma unroll
    for (int k = 0; k < GFULL; ++k) {
        const int l = t + k * BT;
        f4_t y = gr4[gbase + l];
        const int j = 4 * l;
        float cA, vA;
        cA = (j     < G) ? cr0 : cr1;  vA = (j     < G) ? vr0 : vr1;
        acc_gr += exp2f(cA + vA * y.x);
        cA = (j + 1 < G) ? cr0 : cr1;  vA = (j + 1 < G) ? vr0 : vr1;
        acc_gr += exp2f(cA + vA * y.y);
        cA = (j + 2 < G) ? cr0 : cr1;  vA = (j + 2 < G) ? vr0 : vr1;
        acc_gr += exp2f(cA + vA * y.z);
        cA = (j + 3 < G) ? cr0 : cr1;  vA = (j + 3 < G) ? vr0 : vr1;
        acc_gr += exp2f(cA + vA * y.w);
    }
    if (t < GTAIL) {                          // l in [1536, 1667): all row1
        const int l = t + GFULL * BT;
        f4_t y = gr4[gbase + l];
        acc_gr += exp2f(cr1 + vr1 * y.x);
        acc_gr += exp2f(cr1 + vr1 * y.y);
        acc_gr += exp2f(cr1 + vr1 * y.z);
        acc_gr += exp2f(cr1 + vr1 * y.w);
    }

    float v = acc_ev - RES * acc_gr;

    // ---- Block reduction: wave64 shuffle -> LDS -> one atomic per block ---
    #pragma unroll
    for (int off = 32; off > 0; off >>= 1)
        v += __shfl_down(v, off, 64);

    __shared__ float sdata[4];
    const int wave = threadIdx.x >> 6;
    const int lane = threadIdx.x & 63;
    if (lane == 0) sdata[wave] = v;
    __syncthreads();
    if (threadIdx.x == 0) {
        float s = sdata[0] + sdata[1] + sdata[2] + sdata[3];
        atomicAdd(out, s);
    }
}

extern "C" void kernel_launch(void* const* d_in, const int* in_sizes, int n_in,
                              void* d_out, int out_size, void* d_ws, size_t ws_size,
                              hipStream_t stream) {
    const float* ev    = (const float*)d_in[0];  // event_features [S,H,E,1]
    const int*   mask  = (const int*)  d_in[1];  // event_mask     [S,H,E]
    const float* gr    = (const float*)d_in[2];  // grid_features  [S,H,G,1]
    const float* wgt   = (const float*)d_in[3];  // weights        [H,1]
    const float* bases = (const float*)d_in[4];  // bases          [H]
    const float* eff   = (const float*)d_in[5];  // effects        [H,1]
    float* out = (float*)d_out;

    // d_out is poisoned 0xAA before every timed launch — zero it (capture-legal).
    hipMemsetAsync(out, 0, sizeof(float), stream);

    logic_model_kernel<<<NBLK, BT, 0, stream>>>(ev, mask, gr, wgt, bases, eff, out);
}

// Round 7
// 276.012 us; speedup vs baseline: 1.1027x; 1.0575x over previous
//
#include <hip/hip_runtime.h>

// Problem constants: S=4096, H=3, E=512, G=3334, F=1
constexpr int S = 4096;
constexpr int H = 3;
constexpr int E = 512;
constexpr int G = 3334;
constexpr float RES = 0.03f;              // INTEGRAL_RESOLUTION
constexpr float LOG2E = 1.44269504088896340736f;

constexpr int NBLK = 2048;
constexpr int BT   = 256;
constexpr int GPB  = S * H * G / 4 / NBLK;  // 5001 float4 per block (exact)
constexpr int EPB  = S * H * E / 4 / NBLK;  // 768 float4 per block = 3/thread
constexpr int TAIL_T = GPB - 19 * BT;       // 137: slot 19 valid iff t < 137

typedef float f4_t __attribute__((ext_vector_type(4)));
typedef int   i4_t __attribute__((ext_vector_type(4)));

typedef __attribute__((address_space(3))) unsigned char  lds_b;
typedef __attribute__((address_space(1))) const unsigned char glb_b;

// exp(b + w*y) with one magic-div chain per float4; constants log2e-scaled.
__device__ __forceinline__ float quad_exp(int fidx, f4_t y,
                                          float c0, float c1, float c2,
                                          float v0, float v1, float v2) {
    int j = fidx * 4;
    int q = j / G;                        // row (magic-mul)
    int r = j - q * G;                    // col of elem 0
    int m = q - (q / 3) * 3;              // head of elem 0
    int hB = (m == 2) ? 0 : (m + 1);
    float cA = (m == 0) ? c0 : ((m == 1) ? c1 : c2);
    float vA = (m == 0) ? v0 : ((m == 1) ? v1 : v2);
    float cB = (hB == 0) ? c0 : ((hB == 1) ? c1 : c2);
    float vB = (hB == 0) ? v0 : ((hB == 1) ? v1 : v2);
    int lim = G - r;                      // elems >= lim are in row q+1
    float s;
    s  = __expf((cA + vA * y.x) * 0.69314718056f);  // placeholder avoided below
    return s;  // (not used — see quad_exp2)
}

// exp2-form: sum over one float4 at flat float4-index fidx.
__device__ __forceinline__ float quad_exp2(int fidx, f4_t y,
                                           float c0, float c1, float c2,
                                           float v0, float v1, float v2) {
    int j = fidx * 4;
    int q = j / G;
    int r = j - q * G;
    int m = q - (q / 3) * 3;
    int hB = (m == 2) ? 0 : (m + 1);
    float cA = (m == 0) ? c0 : ((m == 1) ? c1 : c2);
    float vA = (m == 0) ? v0 : ((m == 1) ? v1 : v2);
    float cB = (hB == 0) ? c0 : ((hB == 1) ? c1 : c2);
    float vB = (hB == 0) ? v0 : ((hB == 1) ? v1 : v2);
    int lim = G - r;
    float s;
    s  = exp2f(cA + vA * y.x);
    s += exp2f(((1 >= lim) ? cB : cA) + ((1 >= lim) ? vB : vA) * y.y);
    s += exp2f(((2 >= lim) ? cB : cA) + ((2 >= lim) ? vB : vA) * y.z);
    s += exp2f(((3 >= lim) ? cB : cA) + ((3 >= lim) ? vB : vA) * y.w);
    return s;
}

__global__ __launch_bounds__(256) void logic_model_kernel(
    const float* __restrict__ ev,
    const int*   __restrict__ mask,
    const float* __restrict__ gr,
    const float* __restrict__ w,
    const float* __restrict__ bases,
    const float* __restrict__ eff,
    float* __restrict__ out)
{
    const float b0 = bases[0], b1 = bases[1], b2 = bases[2];
    const float w0 = w[0] * eff[0], w1 = w[1] * eff[1], w2 = w[2] * eff[2];
    const float c0 = b0 * LOG2E, c1 = b1 * LOG2E, c2 = b2 * LOG2E;
    const float v0 = w0 * LOG2E, v1 = w1 * LOG2E, v2 = w2 * LOG2E;

    const int t  = threadIdx.x;
    const int b  = blockIdx.x;
    const int wv = t >> 6;                 // wave id (uniform per wave)

    const f4_t* ev4 = (const f4_t*)ev;
    const i4_t* m4  = (const i4_t*)mask;
    const f4_t* gr4 = (const f4_t*)gr;

    // ---- Part 1: events, register path. 3 float4+int4 per thread. --------
    float acc_ev = 0.f;
    {
        const int ebase = b * EPB + t;
        #pragma unroll
        for (int u = 0; u < 3; ++u) {
            int i = ebase + u * BT;
            f4_t x = ev4[i];
            i4_t m = m4[i];
            int row = i >> 7;              // 128 float4 per (s,h) event row
            int h = row - (row / 3) * 3;
            float bb = (h == 0) ? b0 : ((h == 1) ? b1 : b2);
            float ww = (h == 0) ? w0 : ((h == 1) ? w1 : w2);
            if (m.x) acc_ev += bb + ww * x.x;
            if (m.y) acc_ev += bb + ww * x.y;
            if (m.z) acc_ev += bb + ww * x.z;
            if (m.w) acc_ev += bb + ww * x.w;
        }
    }

    // ---- Part 2: hybrid dual-path read. Per iteration k (5 total):
    //   slots 4k,4k+1  -> register loads (VGPR return path)
    //   slots 4k+2,4k+3-> global_load_lds DMA (LDS return path)
    // Block chunk: float4 positions [b*GPB, b*GPB+5001). Slot s covers
    // pos = t + s*256; only slot 19 is partial (t < 137).
    __shared__ f4_t lbuf[512];             // 8 KB: [0..256)=slot 4k+2, [256..512)=slot 4k+3
    const int gbase = b * GPB;
    float acc_gr = 0.f;

    #pragma unroll 1
    for (int k = 0; k < 5; ++k) {
        const int s0 = 4 * k;
        // register-path loads
        f4_t ra = gr4[gbase + t + (s0 + 0) * BT];
        f4_t rb = gr4[gbase + t + (s0 + 1) * BT];
        // DMA-path loads (wave-uniform LDS base; HW adds lane*16)
#if __has_builtin(__builtin_amdgcn_global_load_lds)
        {
            const glb_b* ga = (const glb_b*)(gr4 + gbase + (s0 + 2) * BT + t);
            lds_b* la = (lds_b*)((lds_b*)lbuf + (size_t)wv * 1024);
            __builtin_amdgcn_global_load_lds(ga, la, 16, 0, 0);
            bool full = (s0 + 3 < 19) || (t < TAIL_T);
            if (full) {
                const glb_b* gb2 = (const glb_b*)(gr4 + gbase + (s0 + 3) * BT + t);
                lds_b* lb2 = (lds_b*)((lds_b*)lbuf + 4096 + (size_t)wv * 1024);
                __builtin_amdgcn_global_load_lds(gb2, lb2, 16, 0, 0);
            }
        }
#else
        {
            lbuf[t] = gr4[gbase + (s0 + 2) * BT + t];
            if ((s0 + 3 < 19) || (t < TAIL_T))
                lbuf[256 + t] = gr4[gbase + (s0 + 3) * BT + t];
        }
#endif
        __syncthreads();                   // drains vmem; LDS now valid
        // consume register slots
        acc_gr += quad_exp2(gbase + t + (s0 + 0) * BT, ra, c0, c1, c2, v0, v1, v2);
        acc_gr += quad_exp2(gbase + t + (s0 + 1) * BT, rb, c0, c1, c2, v0, v1, v2);
        // consume LDS slots
        f4_t ya = lbuf[t];
        acc_gr += quad_exp2(gbase + t + (s0 + 2) * BT, ya, c0, c1, c2, v0, v1, v2);
        if ((s0 + 3 < 19) || (t < TAIL_T)) {
            f4_t yb = lbuf[256 + t];
            acc_gr += quad_exp2(gbase + t + (s0 + 3) * BT, yb, c0, c1, c2, v0, v1, v2);
        }
        __syncthreads();                   // protect lbuf before next stage
    }

    float v = acc_ev - RES * acc_gr;

    // ---- Block reduction: wave64 shuffle -> LDS -> one atomic per block ---
    #pragma unroll
    for (int off = 32; off > 0; off >>= 1)
        v += __shfl_down(v, off, 64);

    __shared__ float sdata[4];
    if ((t & 63) == 0) sdata[t >> 6] = v;
    __syncthreads();
    if (t == 0) {
        float s = sdata[0] + sdata[1] + sdata[2] + sdata[3];
        atomicAdd(out, s);
    }
}

extern "C" void kernel_launch(void* const* d_in, const int* in_sizes, int n_in,
                              void* d_out, int out_size, void* d_ws, size_t ws_size,
                              hipStream_t stream) {
    const float* ev    = (const float*)d_in[0];
    const int*   mask  = (const int*)  d_in[1];
    const float* gr    = (const float*)d_in[2];
    const float* wgt   = (const float*)d_in[3];
    const float* bases = (const float*)d_in[4];
    const float* eff   = (const float*)d_in[5];
    float* out = (float*)d_out;

    hipMemsetAsync(out, 0, sizeof(float), stream);
    logic_model_kernel<<<NBLK, BT, 0, stream>>>(ev, mask, gr, wgt, bases, eff, out);
}

// Round 8
// 273.506 us; speedup vs baseline: 1.1128x; 1.0092x over previous
//
#include <hip/hip_runtime.h>

// Problem constants: S=4096, H=3, E=512, G=3334, F=1
constexpr int S = 4096;
constexpr int H = 3;
constexpr int E = 512;
constexpr int G = 3334;
constexpr float RES = 0.03f;              // INTEGRAL_RESOLUTION
constexpr float LOG2E = 1.44269504088896340736f;

constexpr int NBLK = 2048;
constexpr int BT   = 256;
constexpr int GPB  = S * H * G / 4 / NBLK;  // 5001 float4 per block (exact)
constexpr int EPB  = S * H * E / 4 / NBLK;  // 768 float4 per block = 3/thread
constexpr int TAIL_T = GPB - 19 * BT;       // 137: slot 19 valid iff t < 137
// NOTE: 4*GPB = 20004 = 6*G exactly, so each block's grid chunk starts at a
// row boundary and spans exactly 6 rows -> head index is PURELY LOCAL.

typedef float f4_t __attribute__((ext_vector_type(4)));
typedef int   i4_t __attribute__((ext_vector_type(4)));

// Sum of exp2 over one float4 whose LOCAL flat element index is jl (< 20004).
// q = jl/G in [0,6) -> head = q%3 via one compare; in-quad row crossing via lim.
__device__ __forceinline__ float quad_exp2l(int jl, f4_t y,
                                            float c0, float c1, float c2,
                                            float v0, float v1, float v2) {
    int q  = jl / G;                       // small magic-mul (jl < 20004)
    int r  = jl - q * G;
    int m  = (q >= 3) ? (q - 3) : q;       // q % 3, q < 6
    int hB = (m == 2) ? 0 : (m + 1);
    float cA = (m == 0) ? c0 : ((m == 1) ? c1 : c2);
    float vA = (m == 0) ? v0 : ((m == 1) ? v1 : v2);
    float cB = (hB == 0) ? c0 : ((hB == 1) ? c1 : c2);
    float vB = (hB == 0) ? v0 : ((hB == 1) ? v1 : v2);
    int lim = G - r;                       // elems e >= lim belong to row q+1
    float s;
    s  = exp2f(cA + vA * y.x);
    s += exp2f(((1 >= lim) ? cB : cA) + ((1 >= lim) ? vB : vA) * y.y);
    s += exp2f(((2 >= lim) ? cB : cA) + ((2 >= lim) ? vB : vA) * y.z);
    s += exp2f(((3 >= lim) ? cB : cA) + ((3 >= lim) ? vB : vA) * y.w);
    return s;
}

__global__ __launch_bounds__(256) void logic_model_kernel(
    const float* __restrict__ ev,
    const int*   __restrict__ mask,
    const float* __restrict__ gr,
    const float* __restrict__ w,
    const float* __restrict__ bases,
    const float* __restrict__ eff,
    float* __restrict__ partials)          // d_ws: one float per block
{
    const float b0 = bases[0], b1 = bases[1], b2 = bases[2];
    const float w0 = w[0] * eff[0], w1 = w[1] * eff[1], w2 = w[2] * eff[2];
    const float c0 = b0 * LOG2E, c1 = b1 * LOG2E, c2 = b2 * LOG2E;
    const float v0 = w0 * LOG2E, v1 = w1 * LOG2E, v2 = w2 * LOG2E;

    const int t = threadIdx.x;
    const int b = blockIdx.x;

    const f4_t* ev4 = (const f4_t*)ev;
    const i4_t* m4  = (const i4_t*)mask;
    const f4_t* gr4 = (const f4_t*)gr;

    const int ebase = b * EPB + t;
    const int gbase = b * GPB;

    // ---- Prologue: issue Part-1 loads (6) + grid groups 0,1 (8) -----------
    f4_t p1x[3]; i4_t p1m[3];
    #pragma unroll
    for (int u = 0; u < 3; ++u) {
        p1x[u] = ev4[ebase + u * BT];
        p1m[u] = m4[ebase + u * BT];
    }
    f4_t buf[3][4];                        // 3-group rotation, distance-2 pipe
    #pragma unroll
    for (int g = 0; g < 2; ++g)
        #pragma unroll
        for (int u = 0; u < 4; ++u)
            buf[g][u] = gr4[gbase + t + (4 * g + u) * BT];
    __builtin_amdgcn_sched_barrier(0);

    // ---- Part 1: events. Head needs NO divide: row%3 = ((t>>7) + 2u) % 3. -
    float acc_ev = 0.f;
    {
        const bool hi = (t >= 128);
        #pragma unroll
        for (int u = 0; u < 3; ++u) {
            // u=0: h = hi?1:0 ; u=1: h = hi?0:2 ; u=2: h = hi?2:1
            int h = (u == 0) ? (hi ? 1 : 0) : ((u == 1) ? (hi ? 0 : 2) : (hi ? 2 : 1));
            float bb = (h == 0) ? b0 : ((h == 1) ? b1 : b2);
            float ww = (h == 0) ? w0 : ((h == 1) ? w1 : w2);
            f4_t x = p1x[u]; i4_t m = p1m[u];
            if (m.x) acc_ev += bb + ww * x.x;
            if (m.y) acc_ev += bb + ww * x.y;
            if (m.z) acc_ev += bb + ww * x.z;
            if (m.w) acc_ev += bb + ww * x.w;
        }
    }
    __builtin_amdgcn_sched_barrier(0);

    // ---- Part 2: distance-2 fenced pipeline over 5 groups of 4 slots ------
    float acc_gr = 0.f;
    #pragma unroll
    for (int g = 0; g < 5; ++g) {
        if (g + 2 < 5) {                   // issue group g+2 into buf[(g+2)%3]
            #pragma unroll
            for (int u = 0; u < 4; ++u) {
                int slot = 4 * (g + 2) + u;
                int pos  = t + slot * BT;
                int idx  = gbase + ((slot == 19 && t >= TAIL_T) ? 0 : pos);
                buf[(g + 2) % 3][u] = gr4[idx];
            }
        }
        __builtin_amdgcn_sched_barrier(0);
        #pragma unroll
        for (int u = 0; u < 4; ++u) {      // consume group g from buf[g%3]
            int slot = 4 * g + u;
            int pos  = t + slot * BT;
            bool valid = (slot < 19) || (t < TAIL_T);
            int jl = 4 * (valid ? pos : 0);
            float s = quad_exp2l(jl, buf[g % 3][u], c0, c1, c2, v0, v1, v2);
            acc_gr += valid ? s : 0.f;
        }
        __builtin_amdgcn_sched_barrier(0);
    }

    float v = acc_ev - RES * acc_gr;

    // ---- Block reduction -> plain store of per-block partial to d_ws ------
    #pragma unroll
    for (int off = 32; off > 0; off >>= 1)
        v += __shfl_down(v, off, 64);

    __shared__ float sdata[4];
    if ((t & 63) == 0) sdata[t >> 6] = v;
    __syncthreads();
    if (t == 0)
        partials[b] = sdata[0] + sdata[1] + sdata[2] + sdata[3];
}

// Single-block reducer: sums 2048 partials, plain-stores the scalar output.
// (No memset of d_out needed; no device-scope atomics anywhere.)
__global__ __launch_bounds__(256) void reduce_kernel(
    const float* __restrict__ partials, float* __restrict__ out)
{
    const int t = threadIdx.x;
    float v = 0.f;
    #pragma unroll
    for (int k = 0; k < NBLK / BT; ++k)    // 8 loads per thread
        v += partials[t + k * BT];
    #pragma unroll
    for (int off = 32; off > 0; off >>= 1)
        v += __shfl_down(v, off, 64);
    __shared__ float sdata[4];
    if ((t & 63) == 0) sdata[t >> 6] = v;
    __syncthreads();
    if (t == 0)
        out[0] = sdata[0] + sdata[1] + sdata[2] + sdata[3];
}

extern "C" void kernel_launch(void* const* d_in, const int* in_sizes, int n_in,
                              void* d_out, int out_size, void* d_ws, size_t ws_size,
                              hipStream_t stream) {
    const float* ev    = (const float*)d_in[0];
    const int*   mask  = (const int*)  d_in[1];
    const float* gr    = (const float*)d_in[2];
    const float* wgt   = (const float*)d_in[3];
    const float* bases = (const float*)d_in[4];
    const float* eff   = (const float*)d_in[5];
    float* out = (float*)d_out;
    float* partials = (float*)d_ws;        // 2048 floats; overwritten each call

    logic_model_kernel<<<NBLK, BT, 0, stream>>>(ev, mask, gr, wgt, bases, eff,
                                                partials);
    reduce_kernel<<<1, BT, 0, stream>>>(partials, out);
}